// Round 1
// 58.221 us; speedup vs baseline: 1.0321x; 1.0321x over previous
//
#include <hip/hip_runtime.h>
#include <math.h>

// DescriptorBuilder: radial (k=0..8 powers * cosine cutoff) + angular
// (Legendre P0..P2 x (rij*rik)^n, n=0..2) descriptors, N=192 atoms, MIC PBC.
//
// O(N^3) angular triple sum is separable per center i via moments:
//   l=0: S^2,  l=1: |V|^2,  l=2: 1.5*|M|_F^2 - 0.5*S^2
// with w = fc(r)*r^n, S=sum w, V=sum w*u, M=sum w*u u^T (u=dr/r).
// S[n] == q_r[n]; M is symmetric with trace S => Mzz reconstructed, not summed.
//
// Latency-bound regime (192 blocks x 1 wave, <=1 wave/CU): minimize the
// serial chain. Unrolled N=192 fast path batches all position loads up
// front; branchless masked body; unnormalized moments (one v_rcp, no div);
// reduction = 4 DPP VALU steps + 1 ds_swizzle + 1 shfl (66 DS ops vs 216).

namespace {

constexpr float RC_  = 6.0f;
constexpr float RC2_ = RC_ * RC_;
constexpr float PI_F = 3.14159265358979323846f;

struct Ctx {
    float b00, b01, b02, b10, b11, b12, b20, b21, b22;   // box rows
    float i00, i01, i02, i10, i11, i12, i20, i21, i22;   // box^-1 rows
    float six, siy, siz;                                 // center frac coords
    int   i;
};

template<int CTRL>
__device__ __forceinline__ float dpp_add(float v) {
    // v + dpp_permute(v); all lanes valid, bound_ctrl irrelevant but set.
    int t = __builtin_amdgcn_update_dpp(0, __builtin_bit_cast(int, v),
                                        CTRL, 0xF, 0xF, true);
    return v + __builtin_bit_cast(float, t);
}

__device__ __forceinline__ float wave_allreduce(float v) {
    v = dpp_add<0xB1>(v);    // quad_perm [1,0,3,2] : pair sums
    v = dpp_add<0x4E>(v);    // quad_perm [2,3,0,1] : quad sums
    v = dpp_add<0x141>(v);   // row_half_mirror     : 8-group sums
    v = dpp_add<0x140>(v);   // row_mirror          : 16-row sums
    int t = __builtin_amdgcn_ds_swizzle(__builtin_bit_cast(int, v), 0x401F); // xor16
    v += __builtin_bit_cast(float, t);                   // 32-half sums
    v += __shfl_xor(v, 32);                              // full 64-lane sum
    return v;
}

__device__ __forceinline__ void pair_accum(const Ctx& c, int j, bool inb,
                                           float Rjx, float Rjy, float Rjz,
                                           float qr[9], float V[3][3], float M[3][5])
{
    // fractional coords of j
    const float sjx = c.i00 * Rjx + c.i01 * Rjy + c.i02 * Rjz;
    const float sjy = c.i10 * Rjx + c.i11 * Rjy + c.i12 * Rjz;
    const float sjz = c.i20 * Rjx + c.i21 * Rjy + c.i22 * Rjz;
    // minimum image (jnp.round == rint)
    float dsx = c.six - sjx; dsx -= rintf(dsx);
    float dsy = c.siy - sjy; dsy -= rintf(dsy);
    float dsz = c.siz - sjz; dsz -= rintf(dsz);
    const float dx = c.b00 * dsx + c.b01 * dsy + c.b02 * dsz;
    const float dy = c.b10 * dsx + c.b11 * dsy + c.b12 * dsz;
    const float dz = c.b20 * dsx + c.b21 * dsy + c.b22 * dsz;
    const float r2 = dx * dx + dy * dy + dz * dz;

    const bool valid = inb && (j != c.i) && (r2 < RC2_);
    const float rr = valid ? r2 : 1.0f;        // keep sqrt/rcp finite when masked
    const float r  = sqrtf(rr);
    const float ir = __builtin_amdgcn_rcpf(r); // ~1ulp, fine for angular terms
    float fc = 0.5f * (__cosf((PI_F / RC_) * r) + 1.0f);
    fc = valid ? fc : 0.0f;                    // masks every accumulation below

    // radial: q_r[k] += r^k * fc, powers as a log-depth tree
    const float r3 = rr * r;
    const float r4 = rr * rr;
    const float r5 = r4 * r;
    const float r6 = r3 * r3;
    const float r7 = r3 * r4;
    const float r8 = r4 * r4;
    qr[0] += fc;
    qr[1] += fc * r;
    qr[2] += fc * rr;
    qr[3] += fc * r3;
    qr[4] += fc * r4;
    qr[5] += fc * r5;
    qr[6] += fc * r6;
    qr[7] += fc * r7;
    qr[8] += fc * r8;

    // angular moments with unnormalized d:  V[n] += (fc r^{n-1}) d,
    // M[n] += (fc r^{n-2}) d d^T.  g0=h1=fc/r, g1=h2=fc, g2=fc*r, h0=fc/r^2.
    const float h1 = fc * ir;
    const float h0 = h1 * ir;
    const float g2 = fc * r;
    V[0][0] += h1 * dx; V[0][1] += h1 * dy; V[0][2] += h1 * dz;
    V[1][0] += fc * dx; V[1][1] += fc * dy; V[1][2] += fc * dz;
    V[2][0] += g2 * dx; V[2][1] += g2 * dy; V[2][2] += g2 * dz;
    const float dxx = dx * dx, dyy = dy * dy;
    const float dxy = dx * dy, dxz = dx * dz, dyz = dy * dz;
    M[0][0] += h0 * dxx; M[0][1] += h0 * dyy; M[0][2] += h0 * dxy; M[0][3] += h0 * dxz; M[0][4] += h0 * dyz;
    M[1][0] += h1 * dxx; M[1][1] += h1 * dyy; M[1][2] += h1 * dxy; M[1][3] += h1 * dxz; M[1][4] += h1 * dyz;
    M[2][0] += fc * dxx; M[2][1] += fc * dyy; M[2][2] += fc * dxy; M[2][3] += fc * dxz; M[2][4] += fc * dyz;
}

__global__ __launch_bounds__(64)
void desc_kernel(const float* __restrict__ R,
                 const float* __restrict__ box,
                 float* __restrict__ out,
                 int N)
{
    const int i    = blockIdx.x;
    const int lane = threadIdx.x;

    Ctx c;
    c.i = i;
    // box + inverse (uniform; compiler scalarizes)
    c.b00 = box[0]; c.b01 = box[1]; c.b02 = box[2];
    c.b10 = box[3]; c.b11 = box[4]; c.b12 = box[5];
    c.b20 = box[6]; c.b21 = box[7]; c.b22 = box[8];
    const float c00 =  (c.b11 * c.b22 - c.b12 * c.b21);
    const float c10 = -(c.b10 * c.b22 - c.b12 * c.b20);
    const float c20 =  (c.b10 * c.b21 - c.b11 * c.b20);
    const float det = c.b00 * c00 + c.b01 * c10 + c.b02 * c20;
    const float id  = 1.0f / det;
    c.i00 = c00 * id;
    c.i01 = (c.b02 * c.b21 - c.b01 * c.b22) * id;
    c.i02 = (c.b01 * c.b12 - c.b02 * c.b11) * id;
    c.i10 = c10 * id;
    c.i11 = (c.b00 * c.b22 - c.b02 * c.b20) * id;
    c.i12 = (c.b02 * c.b10 - c.b00 * c.b12) * id;
    c.i20 = c20 * id;
    c.i21 = (c.b01 * c.b20 - c.b00 * c.b21) * id;
    c.i22 = (c.b00 * c.b11 - c.b01 * c.b10) * id;

    const float Rix = R[3 * i + 0], Riy = R[3 * i + 1], Riz = R[3 * i + 2];
    c.six = c.i00 * Rix + c.i01 * Riy + c.i02 * Riz;
    c.siy = c.i10 * Rix + c.i11 * Riy + c.i12 * Riz;
    c.siz = c.i20 * Rix + c.i21 * Riy + c.i22 * Riz;

    float qr[9];
    float V[3][3];
    float M[3][5];   // xx, yy, xy, xz, yz  (zz = S - xx - yy)
#pragma unroll
    for (int k = 0; k < 9; ++k) qr[k] = 0.0f;
#pragma unroll
    for (int n = 0; n < 3; ++n) {
#pragma unroll
        for (int q = 0; q < 3; ++q) V[n][q] = 0.0f;
#pragma unroll
        for (int q = 0; q < 5; ++q) M[n][q] = 0.0f;
    }

    if (N == 192) {
        // fast path: batch all 9 neighbor-position loads, single wait,
        // then 3 branchless unrolled bodies
        float px[3], py[3], pz[3];
#pragma unroll
        for (int t = 0; t < 3; ++t) {
            const int j = lane + (t << 6);
            px[t] = R[3 * j + 0];
            py[t] = R[3 * j + 1];
            pz[t] = R[3 * j + 2];
        }
#pragma unroll
        for (int t = 0; t < 3; ++t) {
            const int j = lane + (t << 6);
            pair_accum(c, j, true, px[t], py[t], pz[t], qr, V, M);
        }
    } else {
        for (int j0 = 0; j0 < N; j0 += 64) {
            const int j  = j0 + lane;
            const int jc = (j < N) ? j : 0;
            const float x = R[3 * jc + 0];
            const float y = R[3 * jc + 1];
            const float z = R[3 * jc + 2];
            pair_accum(c, j, j < N, x, y, z, qr, V, M);
        }
    }

    // ---- reduce 33 partials across the wave (VALU DPP + 1 swizzle + 1 shfl) ----
#pragma unroll
    for (int k = 0; k < 9; ++k) qr[k] = wave_allreduce(qr[k]);
#pragma unroll
    for (int n = 0; n < 3; ++n) {
#pragma unroll
        for (int q = 0; q < 3; ++q) V[n][q] = wave_allreduce(V[n][q]);
#pragma unroll
        for (int q = 0; q < 5; ++q) M[n][q] = wave_allreduce(M[n][q]);
    }

    // epilogue (all lanes hold totals; math redundant, store from lane 0)
    float o[18];
#pragma unroll
    for (int k = 0; k < 9; ++k) o[k] = qr[k];
#pragma unroll
    for (int n = 0; n < 3; ++n) {
        const float s   = qr[n];                       // S[n] == q_r[n]
        const float mzz = s - M[n][0] - M[n][1];       // trace identity
        const float v2  = V[n][0] * V[n][0] + V[n][1] * V[n][1] + V[n][2] * V[n][2];
        const float m2  = M[n][0] * M[n][0] + M[n][1] * M[n][1] + mzz * mzz
                  + 2.0f * (M[n][2] * M[n][2] + M[n][3] * M[n][3] + M[n][4] * M[n][4]);
        o[9 + n * 3 + 0] = s * s;                      // P0
        o[9 + n * 3 + 1] = v2;                         // P1
        o[9 + n * 3 + 2] = 1.5f * m2 - 0.5f * s * s;   // P2
    }
    if (lane == 0) {
        float2* o2 = reinterpret_cast<float2*>(out + i * 18);  // 72B rows, 8-aligned
#pragma unroll
        for (int k = 0; k < 9; ++k) o2[k] = make_float2(o[2 * k + 0], o[2 * k + 1]);
    }
}

} // namespace

extern "C" void kernel_launch(void* const* d_in, const int* in_sizes, int n_in,
                              void* d_out, int out_size, void* d_ws, size_t ws_size,
                              hipStream_t stream)
{
    const float* R   = (const float*)d_in[0];   // [N,3] float32
    // d_in[1] = Z (int32) — unused by the reference computation
    const float* box = (const float*)d_in[2];   // [3,3] float32
    float* out = (float*)d_out;                 // [N,18] float32
    const int N = in_sizes[0] / 3;

    desc_kernel<<<dim3(N), dim3(64), 0, stream>>>(R, box, out, N);
}